// Round 5
// baseline (295.502 us; speedup 1.0000x reference)
//
#include <hip/hip_runtime.h>
#include <stdint.h>

#define BATCH 32
#define TLEN  1024
#define DIN   512
#define DOUT  512
#define KW    5
#define TOUT  1020          // TLEN - KW + 1
#define KDIM  (DIN * KW)    // 2560

#define BM 128
#define BN 128
#define BKI 128             // i-chunk staged per barrier phase (4 chunks total)
#define AROWS 144           // staged x rows: 128 outputs + 4 taps (+12 pad for exact grid)

typedef __attribute__((ext_vector_type(8))) short bf16x8;
typedef __attribute__((ext_vector_type(4))) float f32x4;

__device__ __forceinline__ uint16_t f2bf(float f) {
    uint32_t u = __float_as_uint(f);
    uint32_t r = u + 0x7FFFu + ((u >> 16) & 1u);   // RNE to bf16
    return (uint16_t)(r >> 16);
}

// blocks [0,8192): convert x fp32 -> xb bf16, 8 elem/thread, exact
// blocks [8192,13312): pack W -> Wb2 in MFMA B-FRAGMENT order:
//   fragment f = c*80 + j  (c = n/16, j = frag index: j = tap*16 + ic*4 + h
//   over k = tap*512 + ic*128 + h*32 + ...)
//   lane l of fragment f=c*80+j holds W'[n=c*16+(l&15)][k=j*32+(l>>4)*8+e]
//   stored at wb2[f*512 + l*8 + e] -> B-frag load = base + f*1024B + lane*16B
__global__ void convert_pack(const float4* __restrict__ x, uint4* __restrict__ xb,
                             const float* __restrict__ w, uint16_t* __restrict__ wb2) {
    int bid = blockIdx.x;
    if (bid < 8192) {
        int idx = bid * 256 + threadIdx.x;          // 0 .. 2097151 exact
        float4 a = x[2 * idx];
        float4 b = x[2 * idx + 1];
        uint4 v;
        v.x = (uint32_t)f2bf(a.x) | ((uint32_t)f2bf(a.y) << 16);
        v.y = (uint32_t)f2bf(a.z) | ((uint32_t)f2bf(a.w) << 16);
        v.z = (uint32_t)f2bf(b.x) | ((uint32_t)f2bf(b.y) << 16);
        v.w = (uint32_t)f2bf(b.z) | ((uint32_t)f2bf(b.w) << 16);
        xb[idx] = v;
    } else {
        int idx = (bid - 8192) * 256 + threadIdx.x; // 0 .. 1310719 exact
        int f = idx >> 9;           // fragment id
        int l = (idx >> 3) & 63;    // lane within fragment
        int e = idx & 7;            // element within lane's 16 B
        int c = f / 80;
        int j = f - c * 80;
        int n = c * 16 + (l & 15);
        int k = j * 32 + ((l >> 4) * 8) + e;
        int tap = k >> 9;
        int i   = k & 511;
        wb2[idx] = f2bf(w[(n * DIN + i) * KW + tap]);
    }
}

// C[m=(b,t), n=o] = sum_{tap,i} x[b, t+tap, i] * W[o, i, tap]
// A: x rows staged once per i-chunk via global_load_lds (taps = row-shifted frags).
// B: register ping-pong pipeline over pre-fragmented Wb2 (coalesced wave loads,
//    L2-resident, no LDS, prefetched one step ahead -> vmcnt(4)-style overlap).
__global__ void __launch_bounds__(256, 4)
tdnn_gemm(const uint16_t* __restrict__ xb,
          const uint16_t* __restrict__ wb2,
          const float* __restrict__ bias,
          float* __restrict__ out) {
    __shared__ uint16_t As[AROWS * BKI];   // 36 KB; rows 256 B, 16-slot XOR swizzle

    // XCD-aware swizzle: the 4 nb-blocks of one A-tile differ by 8 -> same XCD.
    const int j    = blockIdx.x;       // 0..1023
    const int xcd  = j & 7;
    const int nb   = (j >> 3) & 3;
    const int gi   = j >> 5;           // 0..31
    const int g    = gi * 8 + xcd;     // 0..255
    const int b    = g >> 3;
    const int tb   = g & 7;
    const int t0   = tb * BM;
    const int n0   = nb * BN;

    const int tid  = threadIdx.x;
    const int lane = tid & 63;
    const int w    = tid >> 6;
    const int m_wave = (w & 1) * 64;
    const int n_wave = (w >> 1) * 64;

    const uint16_t* xrow = xb + (size_t)b * TLEN * DIN + (size_t)t0 * DIN;

    const int ml = lane & 15;
    const int kg = lane >> 4;          // 0..3

    // B fragment stream base: c = (n0+n_wave)/16 + ni ; frag = (c0+ni)*80 + j
    const int c0 = (n0 + n_wave) >> 4;
    const uint16_t* bbase = wb2 + (size_t)c0 * 80 * 512 + (size_t)lane * 8;

    f32x4 acc[4][4] = {};

    bf16x8 bfr[2][4];
    int jcur = 0;
    // initial prefetch: step 0 (j=0) into buffer 0
    #pragma unroll
    for (int ni = 0; ni < 4; ++ni)
        bfr[0][ni] = *(const bf16x8*)(bbase + (size_t)ni * 80 * 512);

    for (int ic = 0; ic < 4; ++ic) {
        const int i0 = ic * BKI;
        // ---- stage A: 144 rows x 256 B = 2304 chunks of 16 B, 9/lane exact ----
        #pragma unroll
        for (int it = 0; it < 9; ++it) {
            int c    = w * 576 + it * 64 + lane;
            int row  = c >> 4;
            int slot = c & 15;
            int ccg  = slot ^ (row & 15);
            const uint16_t* gp = xrow + row * DIN + i0 + ccg * 8;
            const uint16_t* lp = &As[(w * 576 + it * 64) * 8];  // wave-uniform base
            __builtin_amdgcn_global_load_lds(
                (const __attribute__((address_space(1))) void*)gp,
                (__attribute__((address_space(3))) void*)lp, 16, 0, 0);
        }
        __syncthreads();

        #pragma unroll
        for (int tap = 0; tap < KW; ++tap) {
            #pragma unroll
            for (int h = 0; h < 4; ++h) {
                // ---- prefetch next step's B frags into the other buffer ----
                // frag index deltas: +1 (h<3), +13 (h==3, tap<4), -63 (wrap to next ic)
                if (tap == 4 && h == 3) {
                    if (ic < 3) {
                        jcur -= 63;
                        #pragma unroll
                        for (int ni = 0; ni < 4; ++ni)
                            bfr[(h + 1) & 1][ni] = *(const bf16x8*)
                                (bbase + (size_t)ni * 80 * 512 + (size_t)jcur * 512);
                    }
                } else {
                    jcur += (h == 3) ? 13 : 1;
                    #pragma unroll
                    for (int ni = 0; ni < 4; ++ni)
                        bfr[(h + 1) & 1][ni] = *(const bf16x8*)
                            (bbase + (size_t)ni * 80 * 512 + (size_t)jcur * 512);
                }

                // ---- A frags: row-shifted by tap, XOR-swizzled slots ----
                const int cc = h * 4 + kg;          // 16B chunk within 256-B row
                bf16x8 af[4];
                #pragma unroll
                for (int mi = 0; mi < 4; ++mi) {
                    int r = m_wave + mi * 16 + ml + tap;
                    af[mi] = *(const bf16x8*)&As[r * BKI + ((cc ^ (r & 15)) * 8)];
                }
                #pragma unroll
                for (int mi = 0; mi < 4; ++mi)
                    #pragma unroll
                    for (int ni = 0; ni < 4; ++ni)
                        acc[mi][ni] = __builtin_amdgcn_mfma_f32_16x16x32_bf16(
                            af[mi], bfr[h & 1][ni], acc[mi][ni], 0, 0, 0);
            }
        }
        __syncthreads();
    }

    // ---- epilogue: D map: col=lane&15, row=(lane>>4)*4+r ; NT stores ----
    const int rq = (lane >> 4) * 4;
    #pragma unroll
    for (int ni = 0; ni < 4; ++ni) {
        int o = n0 + n_wave + ni * 16 + ml;
        float bv = bias[o];
        float* orow = out + ((size_t)b * DOUT + o) * TOUT;
        #pragma unroll
        for (int mi = 0; mi < 4; ++mi) {
            int tbase = t0 + m_wave + mi * 16 + rq;
            #pragma unroll
            for (int r = 0; r < 4; ++r) {
                int t = tbase + r;
                if (t < TOUT) {
                    float v = acc[mi][ni][r] + bv;
                    __builtin_nontemporal_store(v > 0.0f ? v : 0.0f, &orow[t]);
                }
            }
        }
    }
}

extern "C" void kernel_launch(void* const* d_in, const int* in_sizes, int n_in,
                              void* d_out, int out_size, void* d_ws, size_t ws_size,
                              hipStream_t stream) {
    const float* x    = (const float*)d_in[0];
    const float* wgt  = (const float*)d_in[1];
    const float* bias = (const float*)d_in[2];
    float* out = (float*)d_out;

    // ws layout: xb first -> the b=31/tb=7 staged tail over-read (<17 KB past
    // xb end) lands inside wb2 (allocated, values discarded by store guard).
    uint16_t* xb  = (uint16_t*)d_ws;                                  // 33.55 MB
    uint16_t* wb2 = (uint16_t*)((char*)d_ws + (size_t)BATCH * TLEN * DIN * 2);

    convert_pack<<<13312, 256, 0, stream>>>((const float4*)x, (uint4*)xb, wgt, wb2);
    tdnn_gemm<<<1024, 256, 0, stream>>>(xb, wb2, bias, out);
}

// Round 6
// 236.171 us; speedup vs baseline: 1.2512x; 1.2512x over previous
//
#include <hip/hip_runtime.h>
#include <stdint.h>

#define BATCH 32
#define TLEN  1024
#define DIN   512
#define DOUT  512
#define KW    5
#define TOUT  1020          // TLEN - KW + 1
#define KDIM  (DIN * KW)    // 2560

#define BM 128
#define BN 128
#define BKI 128             // i-chunk staged per barrier phase (4 chunks total)
#define AROWS 144           // staged x rows: 128 outputs + 4 taps (+12 pad for exact grid)

typedef __attribute__((ext_vector_type(8))) short bf16x8;
typedef __attribute__((ext_vector_type(4))) float f32x4;

__device__ __forceinline__ uint16_t f2bf(float f) {
    uint32_t u = __float_as_uint(f);
    uint32_t r = u + 0x7FFFu + ((u >> 16) & 1u);   // RNE to bf16
    return (uint16_t)(r >> 16);
}

// blocks [0,8192): convert x fp32 -> xb bf16, 8 elem/thread, exact
// blocks [8192,13312): pack W -> Wb2 in MFMA B-FRAGMENT order:
//   fragment f = c*80 + j  (c = n/16, j = tap*16 + ic*4 + h over k = tap*512+i)
//   lane l of fragment f holds W'[n=c*16+(l&15)][k=j*32+(l>>4)*8+e]
//   stored at wb2[f*512 + l*8 + e] -> B-frag load = base + f*1024B + lane*16B
__global__ void convert_pack(const float4* __restrict__ x, uint4* __restrict__ xb,
                             const float* __restrict__ w, uint16_t* __restrict__ wb2) {
    int bid = blockIdx.x;
    if (bid < 8192) {
        int idx = bid * 256 + threadIdx.x;          // 0 .. 2097151 exact
        float4 a = x[2 * idx];
        float4 b = x[2 * idx + 1];
        uint4 v;
        v.x = (uint32_t)f2bf(a.x) | ((uint32_t)f2bf(a.y) << 16);
        v.y = (uint32_t)f2bf(a.z) | ((uint32_t)f2bf(a.w) << 16);
        v.z = (uint32_t)f2bf(b.x) | ((uint32_t)f2bf(b.y) << 16);
        v.w = (uint32_t)f2bf(b.z) | ((uint32_t)f2bf(b.w) << 16);
        xb[idx] = v;
    } else {
        int idx = (bid - 8192) * 256 + threadIdx.x; // 0 .. 1310719 exact
        int f = idx >> 9;           // fragment id
        int l = (idx >> 3) & 63;    // lane within fragment
        int e = idx & 7;            // element within lane's 16 B
        int c = f / 80;
        int j = f - c * 80;
        int n = c * 16 + (l & 15);
        int k = j * 32 + ((l >> 4) * 8) + e;
        int tap = k >> 9;
        int i   = k & 511;
        wb2[idx] = f2bf(w[(n * DIN + i) * KW + tap]);
    }
}

// C[m=(b,t), n=o] = sum_{tap,i} x[b, t+tap, i] * W[o, i, tap]
// A: x rows staged once per i-chunk via global_load_lds (taps = row-shifted frags).
// B: register ping-pong pipeline over pre-fragmented Wb2 (coalesced wave loads,
//    L2-resident, no LDS, prefetched one step ahead -> vmcnt(4)-style overlap).
// Stores: PLAIN (R5's nontemporal stores doubled WRITE_SIZE via broken L2 merge).
__global__ void __launch_bounds__(256, 4)
tdnn_gemm(const uint16_t* __restrict__ xb,
          const uint16_t* __restrict__ wb2,
          const float* __restrict__ bias,
          float* __restrict__ out) {
    __shared__ uint16_t As[AROWS * BKI];   // 36 KB; rows 256 B, 16-slot XOR swizzle

    // XCD-aware swizzle: the 4 nb-blocks of one A-tile differ by 8 -> same XCD.
    const int j    = blockIdx.x;       // 0..1023
    const int xcd  = j & 7;
    const int nb   = (j >> 3) & 3;
    const int gi   = j >> 5;           // 0..31
    const int g    = gi * 8 + xcd;     // 0..255
    const int b    = g >> 3;
    const int tb   = g & 7;
    const int t0   = tb * BM;
    const int n0   = nb * BN;

    const int tid  = threadIdx.x;
    const int lane = tid & 63;
    const int w    = tid >> 6;
    const int m_wave = (w & 1) * 64;
    const int n_wave = (w >> 1) * 64;

    const uint16_t* xrow = xb + (size_t)b * TLEN * DIN + (size_t)t0 * DIN;

    const int ml = lane & 15;
    const int kg = lane >> 4;          // 0..3

    // B fragment stream base: c = (n0+n_wave)/16 + ni ; frag = (c0+ni)*80 + j
    const int c0 = (n0 + n_wave) >> 4;
    const uint16_t* bbase = wb2 + (size_t)c0 * 80 * 512 + (size_t)lane * 8;

    f32x4 acc[4][4] = {};

    bf16x8 bfr[2][4];
    int jcur = 0;
    // initial prefetch: step 0 (j=0) into buffer 0
    #pragma unroll
    for (int ni = 0; ni < 4; ++ni)
        bfr[0][ni] = *(const bf16x8*)(bbase + (size_t)ni * 80 * 512);

    for (int ic = 0; ic < 4; ++ic) {
        const int i0 = ic * BKI;
        // ---- stage A: 144 rows x 256 B = 2304 chunks of 16 B, 9/lane exact ----
        #pragma unroll
        for (int it = 0; it < 9; ++it) {
            int c    = w * 576 + it * 64 + lane;
            int row  = c >> 4;
            int slot = c & 15;
            int ccg  = slot ^ (row & 15);
            const uint16_t* gp = xrow + row * DIN + i0 + ccg * 8;
            const uint16_t* lp = &As[(w * 576 + it * 64) * 8];  // wave-uniform base
            __builtin_amdgcn_global_load_lds(
                (const __attribute__((address_space(1))) void*)gp,
                (__attribute__((address_space(3))) void*)lp, 16, 0, 0);
        }
        __syncthreads();

        #pragma unroll
        for (int tap = 0; tap < KW; ++tap) {
            #pragma unroll
            for (int h = 0; h < 4; ++h) {
                // ---- prefetch next step's B frags into the other buffer ----
                // frag index deltas: +1 (h<3), +13 (h==3, tap<4), -63 (wrap to next ic)
                if (tap == 4 && h == 3) {
                    if (ic < 3) {
                        jcur -= 63;
                        #pragma unroll
                        for (int ni = 0; ni < 4; ++ni)
                            bfr[(h + 1) & 1][ni] = *(const bf16x8*)
                                (bbase + (size_t)ni * 80 * 512 + (size_t)jcur * 512);
                    }
                } else {
                    jcur += (h == 3) ? 13 : 1;
                    #pragma unroll
                    for (int ni = 0; ni < 4; ++ni)
                        bfr[(h + 1) & 1][ni] = *(const bf16x8*)
                            (bbase + (size_t)ni * 80 * 512 + (size_t)jcur * 512);
                }

                // ---- A frags: row-shifted by tap, XOR-swizzled slots ----
                const int cc = h * 4 + kg;          // 16B chunk within 256-B row
                bf16x8 af[4];
                #pragma unroll
                for (int mi = 0; mi < 4; ++mi) {
                    int r = m_wave + mi * 16 + ml + tap;
                    af[mi] = *(const bf16x8*)&As[r * BKI + ((cc ^ (r & 15)) * 8)];
                }
                #pragma unroll
                for (int mi = 0; mi < 4; ++mi)
                    #pragma unroll
                    for (int ni = 0; ni < 4; ++ni)
                        acc[mi][ni] = __builtin_amdgcn_mfma_f32_16x16x32_bf16(
                            af[mi], bfr[h & 1][ni], acc[mi][ni], 0, 0, 0);
            }
        }
        __syncthreads();
    }

    // ---- epilogue: D map: col=lane&15, row=(lane>>4)*4+r ; plain stores ----
    const int rq = (lane >> 4) * 4;
    #pragma unroll
    for (int ni = 0; ni < 4; ++ni) {
        int o = n0 + n_wave + ni * 16 + ml;
        float bv = bias[o];
        float* orow = out + ((size_t)b * DOUT + o) * TOUT;
        #pragma unroll
        for (int mi = 0; mi < 4; ++mi) {
            int tbase = t0 + m_wave + mi * 16 + rq;
            #pragma unroll
            for (int r = 0; r < 4; ++r) {
                int t = tbase + r;
                if (t < TOUT) {
                    float v = acc[mi][ni][r] + bv;
                    orow[t] = v > 0.0f ? v : 0.0f;
                }
            }
        }
    }
}

extern "C" void kernel_launch(void* const* d_in, const int* in_sizes, int n_in,
                              void* d_out, int out_size, void* d_ws, size_t ws_size,
                              hipStream_t stream) {
    const float* x    = (const float*)d_in[0];
    const float* wgt  = (const float*)d_in[1];
    const float* bias = (const float*)d_in[2];
    float* out = (float*)d_out;

    // ws layout: xb first -> the b=31/tb=7 staged tail over-read (<17 KB past
    // xb end) lands inside wb2 (allocated, values discarded by store guard).
    uint16_t* xb  = (uint16_t*)d_ws;                                  // 33.55 MB
    uint16_t* wb2 = (uint16_t*)((char*)d_ws + (size_t)BATCH * TLEN * DIN * 2);

    convert_pack<<<13312, 256, 0, stream>>>((const float4*)x, (uint4*)xb, wgt, wb2);
    tdnn_gemm<<<1024, 256, 0, stream>>>(xb, wb2, bias, out);
}

// Round 7
// 228.647 us; speedup vs baseline: 1.2924x; 1.0329x over previous
//
#include <hip/hip_runtime.h>
#include <stdint.h>

#define BATCH 32
#define TLEN  1024
#define DIN   512
#define DOUT  512
#define KW    5
#define TOUT  1020          // TLEN - KW + 1
#define KDIM  (DIN * KW)    // 2560

#define BM 128              // t rows per block
#define BN 256              // o cols per block
#define BKI 128             // A i-chunk per phase (4 phases)
#define BKB 64              // B k-chunk per stage
#define AROWS 144           // 128 outputs + 4 taps (+12 pad; 2304 chunks = 9*256)

typedef __attribute__((ext_vector_type(8))) short bf16x8;
typedef __attribute__((ext_vector_type(4))) float f32x4;

__device__ __forceinline__ uint16_t f2bf(float f) {
    uint32_t u = __float_as_uint(f);
    uint32_t r = u + 0x7FFFu + ((u >> 16) & 1u);   // RNE to bf16
    return (uint16_t)(r >> 16);
}

// blocks [0,8192):    convert x fp32 -> xb bf16, 8 elem/thread, exact
// blocks [8192,8704): o = bid-8192; pack W[o,:,:] -> Wb[o][tap*512+i]
//                     coalesced read + LDS transpose + coalesced write (R2-proven)
__global__ void convert_pack(const float4* __restrict__ x, uint4* __restrict__ xb,
                             const float* __restrict__ w, uint16_t* __restrict__ wb) {
    __shared__ uint16_t sW[KDIM];      // 5 KB, pack path only
    int bid = blockIdx.x;
    if (bid < 8192) {
        int idx = bid * 256 + threadIdx.x;          // 0 .. 2097151 exact
        float4 a = x[2 * idx];
        float4 b = x[2 * idx + 1];
        uint4 v;
        v.x = (uint32_t)f2bf(a.x) | ((uint32_t)f2bf(a.y) << 16);
        v.y = (uint32_t)f2bf(a.z) | ((uint32_t)f2bf(a.w) << 16);
        v.z = (uint32_t)f2bf(b.x) | ((uint32_t)f2bf(b.y) << 16);
        v.w = (uint32_t)f2bf(b.z) | ((uint32_t)f2bf(b.w) << 16);
        xb[idx] = v;
    } else {
        int o = bid - 8192;                         // 0..511
        #pragma unroll
        for (int r = 0; r < 10; ++r) {
            int idx = r * 256 + threadIdx.x;        // flat (i,k), coalesced
            sW[idx] = f2bf(w[o * KDIM + idx]);
        }
        __syncthreads();
        #pragma unroll
        for (int r = 0; r < 10; ++r) {
            int kk = r * 256 + threadIdx.x;         // out idx tap*512+i, coalesced
            int i = kk & 511;
            int k = kk >> 9;
            wb[o * KDIM + kk] = sW[i * 5 + k];
        }
    }
}

// C[m=(b,t), n=o] = sum_{tap,i} x[b, t+tap, i] * W[o, i, tap]
// Geometry: 128x256 block, 4 waves of 64x128 (acc 4x8 f32x4 = 128 AGPRs).
// A: conv-structure staging — x rows [t0,t0+144) x 128-i staged ONCE per ic
//    phase (36 KB, 16-slot XOR); taps realized as row-shifted fragment reads.
// B: LDS-staged per 64-k chunk (32 KB, 8-slot XOR; R2-proven, 0 conflicts).
__global__ void __launch_bounds__(256, 2)
tdnn_gemm(const uint16_t* __restrict__ xb,
          const uint16_t* __restrict__ wb,
          const float* __restrict__ bias,
          float* __restrict__ out) {
    __shared__ uint16_t As[AROWS * BKI];   // 36 KB; 256-B rows, 16-slot XOR
    __shared__ uint16_t Bs[BN * BKB];      // 32 KB; 128-B rows, 8-slot XOR

    // XCD swizzle: the 2 nb-blocks sharing an A-tile differ by 8 -> same XCD.
    const int j    = blockIdx.x;       // 0..511
    const int xcd  = j & 7;
    const int nb   = (j >> 3) & 1;
    const int gi   = j >> 4;           // 0..31
    const int g    = gi * 8 + xcd;     // 0..255
    const int b    = g >> 3;
    const int tb   = g & 7;
    const int t0   = tb * BM;
    const int n0   = nb * BN;

    const int tid  = threadIdx.x;
    const int lane = tid & 63;
    const int w    = tid >> 6;
    const int m_wave = (w & 1) * 64;
    const int n_wave = (w >> 1) * 128;

    const uint16_t* xrow = xb + (size_t)b * TLEN * DIN + (size_t)t0 * DIN;

    const int ml = lane & 15;
    const int kg = lane >> 4;          // 0..3

    f32x4 acc[4][8] = {};

    for (int ic = 0; ic < 4; ++ic) {
        const int i0 = ic * BKI;
        #pragma unroll
        for (int tap = 0; tap < KW; ++tap) {
            #pragma unroll
            for (int hb = 0; hb < 2; ++hb) {
                // ---- stage B chunk: 256 rows x 64 k (2048 chunks, 8/thread) ----
                const int k0 = tap * 512 + i0 + hb * 64;
                #pragma unroll
                for (int ib = 0; ib < 8; ++ib) {
                    int c    = w * 512 + ib * 64 + lane;
                    int row  = c >> 3;
                    int slot = c & 7;
                    int ccg  = slot ^ (row & 7);
                    const uint16_t* gp = wb + (size_t)(n0 + row) * KDIM + k0 + ccg * 8;
                    const uint16_t* lp = &Bs[(w * 512 + ib * 64) * 8];
                    __builtin_amdgcn_global_load_lds(
                        (const __attribute__((address_space(1))) void*)gp,
                        (__attribute__((address_space(3))) void*)lp, 16, 0, 0);
                }
                // ---- stage A once per ic phase (2304 chunks, 9/thread) ----
                if (tap == 0 && hb == 0) {
                    #pragma unroll
                    for (int it = 0; it < 9; ++it) {
                        int c    = w * 576 + it * 64 + lane;
                        int row  = c >> 4;
                        int slot = c & 15;
                        int ccg  = slot ^ (row & 15);
                        const uint16_t* gp = xrow + row * DIN + i0 + ccg * 8;
                        const uint16_t* lp = &As[(w * 576 + it * 64) * 8];
                        __builtin_amdgcn_global_load_lds(
                            (const __attribute__((address_space(1))) void*)gp,
                            (__attribute__((address_space(3))) void*)lp, 16, 0, 0);
                    }
                }
                __syncthreads();

                // ---- compute on the 64-k chunk: 2 k-steps of 32 ----
                #pragma unroll
                for (int h = 0; h < 2; ++h) {
                    const int cc  = (hb * 2 + h) * 4 + kg;   // A chunk 0..15
                    const int bcc = h * 4 + kg;              // B chunk 0..7
                    bf16x8 af[4];
                    #pragma unroll
                    for (int mi = 0; mi < 4; ++mi) {
                        int r = m_wave + mi * 16 + ml + tap;
                        af[mi] = *(const bf16x8*)&As[r * BKI + ((cc ^ (r & 15)) * 8)];
                    }
                    bf16x8 bfr[8];
                    #pragma unroll
                    for (int ni = 0; ni < 8; ++ni) {
                        int rn = n_wave + ni * 16 + ml;
                        bfr[ni] = *(const bf16x8*)&Bs[rn * BKB + ((bcc ^ (rn & 7)) * 8)];
                    }
                    #pragma unroll
                    for (int mi = 0; mi < 4; ++mi)
                        #pragma unroll
                        for (int ni = 0; ni < 8; ++ni)
                            acc[mi][ni] = __builtin_amdgcn_mfma_f32_16x16x32_bf16(
                                af[mi], bfr[ni], acc[mi][ni], 0, 0, 0);
                }
                __syncthreads();
            }
        }
    }

    // ---- epilogue: D map: col=lane&15, row=(lane>>4)*4+r ; plain stores ----
    const int rq = (lane >> 4) * 4;
    #pragma unroll
    for (int ni = 0; ni < 8; ++ni) {
        int o = n0 + n_wave + ni * 16 + ml;
        float bv = bias[o];
        float* orow = out + ((size_t)b * DOUT + o) * TOUT;
        #pragma unroll
        for (int mi = 0; mi < 4; ++mi) {
            int tbase = t0 + m_wave + mi * 16 + rq;
            #pragma unroll
            for (int r = 0; r < 4; ++r) {
                int t = tbase + r;
                if (t < TOUT) {
                    float v = acc[mi][ni][r] + bv;
                    orow[t] = v > 0.0f ? v : 0.0f;
                }
            }
        }
    }
}

extern "C" void kernel_launch(void* const* d_in, const int* in_sizes, int n_in,
                              void* d_out, int out_size, void* d_ws, size_t ws_size,
                              hipStream_t stream) {
    const float* x    = (const float*)d_in[0];
    const float* wgt  = (const float*)d_in[1];
    const float* bias = (const float*)d_in[2];
    float* out = (float*)d_out;

    // ws layout: xb first -> the b=31/tb=7 staged-A tail over-read (<17 KB past
    // xb end) lands inside wb (allocated; values masked by the t<1020 guard).
    uint16_t* xb = (uint16_t*)d_ws;                                   // 33.55 MB
    uint16_t* wb = (uint16_t*)((char*)d_ws + (size_t)BATCH * TLEN * DIN * 2);

    convert_pack<<<8704, 256, 0, stream>>>((const float4*)x, (uint4*)xb, wgt, wb);
    tdnn_gemm<<<512, 256, 0, stream>>>(xb, wb, bias, out);
}